// Round 8
// baseline (178.425 us; speedup 1.0000x reference)
//
#include <hip/hip_runtime.h>
#include <hip/hip_bf16.h>
#include <math.h>

#define BB 8
#define NN 2048
#define DD 128
#define LL 3
#define GN_EPS 1e-5f

typedef __attribute__((ext_vector_type(8))) short bf16x8;
typedef __attribute__((ext_vector_type(4))) float f32x4;
typedef __attribute__((ext_vector_type(8))) unsigned short u16x8;

// raw v_sqrt_f32 (1 inst)
#define FSQRT(x) __builtin_amdgcn_sqrtf(x)

// round-half-up f32 -> bf16 bits
__device__ __forceinline__ unsigned short f2bf(float f) {
    union { float f; unsigned u; } v; v.f = f;
    return (unsigned short)((v.u + 0x8000u) >> 16);
}

__device__ __forceinline__ float fast_tanh(float x) {
    float e = __expf(-2.0f * fabsf(x));
    float t = (1.0f - e) * __builtin_amdgcn_rcpf(1.0f + e);
    return copysignf(t, x);
}

// GraphNorm affine fold: h_norm = s*h + c
__device__ __forceinline__ void stats_sc(float ps, float pq, float a, float w_,
                                         float b_, float& s, float& c) {
    const float inv_n = 1.0f / (float)NN;
    float mean = ps * inv_n;
    float msq  = pq * inv_n;
    float var  = msq - mean * mean * a * (2.0f - a);
    float rstd = rsqrtf(var + GN_EPS);
    s = w_ * rstd;
    c = b_ - s * (a * mean);
}

// Packed layout (16B granule = one lane's bf16x8 frag slice):
//  tp[b][kcg(64)][dt(8)][lane(64)]  value[j] = dinv*lin(h)[d=dt*16+ll][m=kcg*32+lq*8+j]
// A is never materialized in HBM: agg regenerates dist frags from coords in LDS.

// ---------------------------------------------------------------------------
// K0: prep_wg — pack Wg (3x128x128 f32) into bf16 MFMA frag order.
// Block 0 additionally folds layer-0 lin: Weff = Wg0·Wn (128x2, f32),
// beff = Wg0·bn — lets gen_pack emit tp0 directly (lin0 kernel removed).
// ---------------------------------------------------------------------------
__global__ __launch_bounds__(256)
void prep_wg(const float* __restrict__ Wg, const float* __restrict__ Wn,
             const float* __restrict__ bn, unsigned short* __restrict__ wgf,
             float* __restrict__ weff, float* __restrict__ beff)
{
    const int f = blockIdx.x * 256 + threadIdx.x;    // < 3*128*128
    const int l  = f >> 14;
    const int r  = f & 16383;
    const int dp = r >> 7;
    const int e  = r & 127;
    const int dpt = dp >> 4, ll = dp & 15;
    const int kc  = e >> 5,  eo = e & 31;
    wgf[((((l * 8 + dpt) * 4 + kc) * 16 + ll) << 5) + eo] = f2bf(Wg[f]);

    if (blockIdx.x == 0 && threadIdx.x < 128) {
        const int ee = threadIdx.x;
        float a0 = 0.f, a1 = 0.f, cc = 0.f;
        for (int d = 0; d < 128; ++d) {
            const float wv = Wg[ee * 128 + d];       // layer 0 slice
            a0 = fmaf(wv, Wn[d * 2 + 0], a0);
            a1 = fmaf(wv, Wn[d * 2 + 1], a1);
            cc = fmaf(wv, bn[d], cc);
        }
        weff[ee * 2 + 0] = a0;
        weff[ee * 2 + 1] = a1;
        beff[ee] = cc;
    }
}

// ---------------------------------------------------------------------------
// K1: gen_pack — deg/dinv (full dist row-sums, f32), proj_node h-init, and
// tp0 (layer-0 lin folded via Weff/beff).  NO Ap store — agg regenerates A.
// grid 1024 = [ntile(7b)<<3 | b(3b)].
// ---------------------------------------------------------------------------
__global__ __launch_bounds__(256)
void gen_pack(const float* __restrict__ inst, const float* __restrict__ Wn,
              const float* __restrict__ bn, const float* __restrict__ weff,
              const float* __restrict__ beff,
              float* __restrict__ dinv, float* __restrict__ h,
              unsigned short* __restrict__ tp,
              float* __restrict__ psum, float* __restrict__ psq)
{
    __shared__ float cs[NN * 2];          // 16 KB coords
    __shared__ float part[4][16];
    const int b     = blockIdx.x & 7;
    const int ntile = blockIdx.x >> 3;    // 0..127
    const int n0    = ntile * 16;
    const int tid   = threadIdx.x;
    const int w     = tid >> 6;
    const int lane  = tid & 63;
    const int lq    = lane >> 4;
    const int ll    = lane & 15;

    const float* instb = inst + b * NN * 2;
    for (int i = tid; i < (NN * 2) / 4; i += 256)
        ((float4*)cs)[i] = ((const float4*)instb)[i];
    __syncthreads();

    const int n = n0 + ll;
    const float nx = cs[n * 2 + 0];
    const float ny = cs[n * 2 + 1];

    const int diagkcg = ntile >> 1;       // kcg whose m-range contains n0..n0+15
    float rs = 0.f;
    for (int kc = 0; kc < 16; ++kc) {
        const int kcg = w * 16 + kc;
        const int mb  = kcg * 32 + lq * 8;
        const float* cp = &cs[mb * 2];
        float4 c01 = *(const float4*)(cp + 0);
        float4 c23 = *(const float4*)(cp + 4);
        float4 c45 = *(const float4*)(cp + 8);
        float4 c67 = *(const float4*)(cp + 12);
        float mxx[8] = { c01.x, c01.z, c23.x, c23.z, c45.x, c45.z, c67.x, c67.z };
        float myy[8] = { c01.y, c01.w, c23.y, c23.w, c45.y, c45.w, c67.y, c67.w };
        float dist[8];
        #pragma unroll
        for (int j = 0; j < 8; ++j) {
            float dx = nx - mxx[j];
            float dy = ny - myy[j];
            dist[j] = FSQRT(dx * dx + dy * dy);
        }
        if (kcg == diagkcg) {
            #pragma unroll
            for (int j = 0; j < 8; ++j)
                if (mb + j == n) dist[j] = 1.0f;       // self-loop
        }
        #pragma unroll
        for (int j = 0; j < 8; ++j) rs += dist[j];
    }

    rs += __shfl_xor(rs, 16);
    rs += __shfl_xor(rs, 32);
    if (lq == 0) part[w][ll] = rs;
    __syncthreads();
    if (tid < 16)
        dinv[b * NN + n0 + tid] = rsqrtf(part[0][tid] + part[1][tid] +
                                         part[2][tid] + part[3][tid]);

    // fused proj h-init + tp0 (layer-0 lin folded, dinv from part[])
    {
        const int d  = tid & 127;
        const int r0 = tid >> 7;          // 0/1
        const float w0 = Wn[d * 2 + 0];
        const float w1 = Wn[d * 2 + 1];
        const float bv = bn[d];
        const float we0 = weff[d * 2 + 0];
        const float we1 = weff[d * 2 + 1];
        const float be  = beff[d];
        const int kcg   = ntile >> 1;
        const int mbase = (ntile & 1) * 16;
        const int dt    = d >> 4;
        const int lld   = d & 15;
        unsigned short* tpd =
            tp + (((size_t)(b * 64 + kcg) * 8 + dt) * 64 + lld) * 8;
        #pragma unroll
        for (int r = r0; r < 16; r += 2) {
            const float x0 = cs[(n0 + r) * 2 + 0];
            const float x1 = cs[(n0 + r) * 2 + 1];
            h[((size_t)b * NN + n0 + r) * DD + d] = fmaf(x0, w0, fmaf(x1, w1, bv));
            const float dv = rsqrtf(part[0][r] + part[1][r] + part[2][r] + part[3][r]);
            const int mloc = mbase + r;
            const int lqa  = mloc >> 3;
            const int j    = mloc & 7;
            tpd[(size_t)lqa * 128 + j] = f2bf(dv * fmaf(x0, we0, fmaf(x1, we1, be)));
        }
    }
    if (blockIdx.x == 0) {
        for (int i = tid; i < LL * BB * DD; i += 256) { psum[i] = 0.f; psq[i] = 0.f; }
    }
}

// ---------------------------------------------------------------------------
// K3: lin (MFMA).  Writes tp in agg's packed frag order.  (layers 1,2 only)
// blockIdx = [tile(6b)<<3 | b(3b)] (batch -> XCD, same as agg).
// ---------------------------------------------------------------------------
template <bool HP>
__global__ __launch_bounds__(256)
void lin_mfma(const float* __restrict__ h, const unsigned short* __restrict__ wgf_l,
              const float* __restrict__ dinv,
              const float* __restrict__ psumP, const float* __restrict__ psqP,
              const float* __restrict__ ga, const float* __restrict__ gw,
              const float* __restrict__ gb, unsigned short* __restrict__ tp)
{
    __shared__ float sL[DD], cL[DD];
    const int tid  = threadIdx.x;
    const int b    = blockIdx.x & 7;
    const int tile = blockIdx.x >> 3;
    const int row0 = b * NN + tile * 32;
    const int w    = tid >> 6;
    const int lane = tid & 63;
    const int lq   = lane >> 4;
    const int ll   = lane & 15;

    if (tid < DD) {
        float s = 1.0f, c = 0.0f;
        if (HP)
            stats_sc(psumP[b * DD + tid], psqP[b * DD + tid],
                     ga[tid], gw[tid], gb[tid], s, c);
        sL[tid] = s; cL[tid] = c;
    }
    __syncthreads();

    bf16x8 aw[2][4];
    #pragma unroll
    for (int mt = 0; mt < 2; ++mt) {
        const int dpt = 2 * w + mt;
        #pragma unroll
        for (int kc = 0; kc < 4; ++kc)
            aw[mt][kc] = *(const bf16x8*)&wgf_l[(((dpt * 4 + kc) * 16 + ll) << 5) + lq * 8];
    }

    bf16x8 bh[2][4];
    #pragma unroll
    for (int nt = 0; nt < 2; ++nt) {
        const float* hrow = h + (size_t)(row0 + nt * 16 + ll) * DD;
        #pragma unroll
        for (int kc = 0; kc < 4; ++kc) {
            float4 h0 = *(const float4*)&hrow[kc * 32 + lq * 8];
            float4 h1 = *(const float4*)&hrow[kc * 32 + lq * 8 + 4];
            const int e0 = kc * 32 + lq * 8;
            bf16x8 p;
            p[0] = (short)f2bf(fmaf(sL[e0 + 0], h0.x, cL[e0 + 0]));
            p[1] = (short)f2bf(fmaf(sL[e0 + 1], h0.y, cL[e0 + 1]));
            p[2] = (short)f2bf(fmaf(sL[e0 + 2], h0.z, cL[e0 + 2]));
            p[3] = (short)f2bf(fmaf(sL[e0 + 3], h0.w, cL[e0 + 3]));
            p[4] = (short)f2bf(fmaf(sL[e0 + 4], h1.x, cL[e0 + 4]));
            p[5] = (short)f2bf(fmaf(sL[e0 + 5], h1.y, cL[e0 + 5]));
            p[6] = (short)f2bf(fmaf(sL[e0 + 6], h1.z, cL[e0 + 6]));
            p[7] = (short)f2bf(fmaf(sL[e0 + 7], h1.w, cL[e0 + 7]));
            bh[nt][kc] = p;
        }
    }

    f32x4 acc[2][2];   // [nt][mt]
    #pragma unroll
    for (int i = 0; i < 2; ++i)
        #pragma unroll
        for (int j = 0; j < 2; ++j) acc[i][j] = (f32x4)0.0f;

    #pragma unroll
    for (int kc = 0; kc < 4; ++kc)
        #pragma unroll
        for (int nt = 0; nt < 2; ++nt)
            #pragma unroll
            for (int mt = 0; mt < 2; ++mt)
                acc[nt][mt] = __builtin_amdgcn_mfma_f32_16x16x32_bf16(
                    bh[nt][kc], aw[mt][kc], acc[nt][mt], 0, 0, 0);

    // packed store: value (dp=(2w+mt)*16+ll, m = tile*32+nt*16+lq*4+reg)
    #pragma unroll
    for (int nt = 0; nt < 2; ++nt) {
        const int mloc0 = nt * 16 + lq * 4;            // m within the kcg=tile chunk
        const int lq_a  = mloc0 >> 3;
        const int j0    = mloc0 & 7;
        float4 di4 = *(const float4*)&dinv[row0 + mloc0];
        #pragma unroll
        for (int mt = 0; mt < 2; ++mt) {
            const int dt = 2 * w + mt;
            ushort4 pk;
            pk.x = f2bf(acc[nt][mt][0] * di4.x);
            pk.y = f2bf(acc[nt][mt][1] * di4.y);
            pk.z = f2bf(acc[nt][mt][2] * di4.z);
            pk.w = f2bf(acc[nt][mt][3] * di4.w);
            *(ushort4*)&tp[((size_t)((b * 64 + tile) * 8 + dt) * 64 + lq_a * 16 + ll) * 8 + j0] = pk;
        }
    }
}

// ---------------------------------------------------------------------------
// K4: agg — 32n x 128d tile, grid 512 (2 blocks/CU), 256 thr, 4 waves d-split.
// R7's double-buffered A-plane with GEN/USE interleave (4 phases x 4 K-steps)
// PLUS: (1) B prefetch at DISTANCE 2 via 3-buffer static rotation (~700 cyc
// of L2/L3 latency cover vs ~300 at distance 1); (2) s_setprio(1) around each
// 8-MFMA cluster (T5 — pays off now that GEN/MFMA role diversity exists
// between co-resident waves).  MFMA accumulation order unchanged (bit-exact).
// LDS 80 KB = 16 coords + 2x32 planes; 2 blocks/CU.
// ---------------------------------------------------------------------------
template <bool HP>
__global__ __launch_bounds__(256, 2)
void agg_mfma(const float* __restrict__ inst, const unsigned short* __restrict__ tp,
              const float* __restrict__ dinv, const float* __restrict__ bg_l,
              const float* __restrict__ psumP, const float* __restrict__ psqP,
              const float* __restrict__ ga, const float* __restrict__ gw,
              const float* __restrict__ gb,
              float* __restrict__ h, float* __restrict__ psum, float* __restrict__ psq)
{
    __shared__ float cs[NN * 2];                         // 16 KB coords
    __shared__ __align__(16) char plane[2][32768];       // 2 x 32 KB A-frag planes
    const int b    = blockIdx.x & 7;
    const int t2   = blockIdx.x >> 3;     // 0..63 (32-row tile)
    const int n0   = t2 * 32;
    const int tid  = threadIdx.x;
    const int w    = tid >> 6;
    const int lane = tid & 63;
    const int lq   = lane >> 4;
    const int ll   = lane & 15;

    // stage coords
    const float* instb = inst + b * NN * 2;
    for (int i = tid; i < (NN * 2) / 4; i += 256)
        ((float4*)cs)[i] = ((const float4*)instb)[i];

    const unsigned short* tpb = tp + ((size_t)b * 64 * 8) * 512 + lane * 8;

    f32x4 acc[2][2];   // [nt][dtl]
    acc[0][0] = (f32x4)0.0f; acc[0][1] = (f32x4)0.0f;
    acc[1][0] = (f32x4)0.0f; acc[1][1] = (f32x4)0.0f;

    // statically-named B triple buffer (dtl split), rotation period 3:
    // K-step k uses pair (k%3): 0->A, 1->B, 2->C; load K=k+2 into ((k+2)%3).
    bf16x8 fbA0[4], fbA1[4], fbB0[4], fbB1[4], fbC0[4], fbC1[4];

    __syncthreads();      // coords visible

    // this lane's two output rows (nt=0/1) — diag lives at kcg == t2
    const int   nr0 = n0 + ll;
    const int   nr1 = n0 + 16 + ll;
    const float nx0 = cs[nr0 * 2 + 0], ny0 = cs[nr0 * 2 + 1];
    const float nx1 = cs[nr1 * 2 + 0], ny1 = cs[nr1 * 2 + 1];

#define LOADB_INTO(B0, B1, KK) { \
        _Pragma("unroll") \
        for (int s_ = 0; s_ < 4; ++s_) { \
            B0[s_] = *(const bf16x8*)(tpb + (size_t)(((KK) * 4 + s_) * 8 + 2 * w + 0) * 512); \
            B1[s_] = *(const bf16x8*)(tpb + (size_t)(((KK) * 4 + s_) * 8 + 2 * w + 1) * 512); \
        } \
    }

    // GENQ: frag q (0..3) of phase PH -> plane[PL].  kcg = PH*16 + w*4 + q.
    // plane slot for (step I = w, nt, s = q): (w*8 + nt*4 + q) * 1KB.
#define GENQ(PL, PH, Q) { \
        const int kcg_ = (PH) * 16 + w * 4 + (Q); \
        const int mb_  = kcg_ * 32 + lq * 8; \
        const float* cp_ = &cs[mb_ * 2]; \
        float4 c01 = *(const float4*)(cp_ + 0); \
        float4 c23 = *(const float4*)(cp_ + 4); \
        float4 c45 = *(const float4*)(cp_ + 8); \
        float4 c67 = *(const float4*)(cp_ + 12); \
        float mxx[8] = { c01.x, c01.z, c23.x, c23.z, c45.x, c45.z, c67.x, c67.z }; \
        float myy[8] = { c01.y, c01.w, c23.y, c23.w, c45.y, c45.w, c67.y, c67.w }; \
        float dv0[8], dv1[8]; \
        _Pragma("unroll") \
        for (int j = 0; j < 8; ++j) { \
            float dx0 = nx0 - mxx[j], dy0 = ny0 - myy[j]; \
            dv0[j] = FSQRT(dx0 * dx0 + dy0 * dy0); \
            float dx1 = nx1 - mxx[j], dy1 = ny1 - myy[j]; \
            dv1[j] = FSQRT(dx1 * dx1 + dy1 * dy1); \
        } \
        if (kcg_ == t2) {   /* wave-uniform diag fixup */ \
            _Pragma("unroll") \
            for (int j = 0; j < 8; ++j) { \
                if (mb_ + j == nr0) dv0[j] = 1.0f; \
                if (mb_ + j == nr1) dv1[j] = 1.0f; \
            } \
        } \
        u16x8 pk0, pk1; \
        _Pragma("unroll") \
        for (int j = 0; j < 8; ++j) { pk0[j] = f2bf(dv0[j]); pk1[j] = f2bf(dv1[j]); } \
        *(u16x8*)(plane[PL] + (w * 8 + 0 + (Q)) * 1024 + lane * 16) = pk0; \
        *(u16x8*)(plane[PL] + (w * 8 + 4 + (Q)) * 1024 + lane * 16) = pk1; \
    }

    // STEP: af from plane[PL] step I, optional B prefetch (distance 2),
    // 16 MFMA on U0/U1 wrapped in setprio(1)/(0).
#define STEP(PL, I, U0, U1, DOLOAD, L0, L1, KN) { \
        bf16x8 af[2][4]; \
        _Pragma("unroll") \
        for (int nt = 0; nt < 2; ++nt) \
            _Pragma("unroll") \
            for (int s = 0; s < 4; ++s) \
                af[nt][s] = *(const bf16x8*)(plane[PL] + (((I) * 8 + nt * 4 + s) * 1024) + lane * 16); \
        if (DOLOAD) LOADB_INTO(L0, L1, KN) \
        __builtin_amdgcn_s_setprio(1); \
        _Pragma("unroll") \
        for (int s = 0; s < 4; ++s) \
            _Pragma("unroll") \
            for (int nt = 0; nt < 2; ++nt) { \
                acc[nt][0] = __builtin_amdgcn_mfma_f32_16x16x32_bf16(U0[s], af[nt][s], acc[nt][0], 0, 0, 0); \
                acc[nt][1] = __builtin_amdgcn_mfma_f32_16x16x32_bf16(U1[s], af[nt][s], acc[nt][1], 0, 0, 0); \
            } \
        __builtin_amdgcn_s_setprio(0); \
    }

    // prologue: phase-0 frags + B(0), B(1) in flight (distance 2)
    GENQ(0, 0, 0) GENQ(0, 0, 1) GENQ(0, 0, 2) GENQ(0, 0, 3)
    LOADB_INTO(fbA0, fbA1, 0)
    LOADB_INTO(fbB0, fbB1, 1)
    __syncthreads();

    // phase 0: K 0..3 from plane0; GEN phase1 -> plane1 (interleaved)
    STEP(0, 0, fbA0, fbA1, true, fbC0, fbC1, 2)   GENQ(1, 1, 0)
    STEP(0, 1, fbB0, fbB1, true, fbA0, fbA1, 3)   GENQ(1, 1, 1)
    STEP(0, 2, fbC0, fbC1, true, fbB0, fbB1, 4)   GENQ(1, 1, 2)
    STEP(0, 3, fbA0, fbA1, true, fbC0, fbC1, 5)   GENQ(1, 1, 3)
    __syncthreads();

    // phase 1: K 4..7 from plane1; GEN phase2 -> plane0
    STEP(1, 0, fbB0, fbB1, true, fbA0, fbA1, 6)   GENQ(0, 2, 0)
    STEP(1, 1, fbC0, fbC1, true, fbB0, fbB1, 7)   GENQ(0, 2, 1)
    STEP(1, 2, fbA0, fbA1, true, fbC0, fbC1, 8)   GENQ(0, 2, 2)
    STEP(1, 3, fbB0, fbB1, true, fbA0, fbA1, 9)   GENQ(0, 2, 3)
    __syncthreads();

    // phase 2: K 8..11 from plane0; GEN phase3 -> plane1
    STEP(0, 0, fbC0, fbC1, true, fbB0, fbB1, 10)  GENQ(1, 3, 0)
    STEP(0, 1, fbA0, fbA1, true, fbC0, fbC1, 11)  GENQ(1, 3, 1)
    STEP(0, 2, fbB0, fbB1, true, fbA0, fbA1, 12)  GENQ(1, 3, 2)
    STEP(0, 3, fbC0, fbC1, true, fbB0, fbB1, 13)  GENQ(1, 3, 3)
    __syncthreads();

    // phase 3: K 12..15 from plane1; drain (loads for K14,K15 issued at 12,13)
    STEP(1, 0, fbA0, fbA1, true,  fbC0, fbC1, 14)
    STEP(1, 1, fbB0, fbB1, true,  fbA0, fbA1, 15)
    STEP(1, 2, fbC0, fbC1, false, fbA0, fbA1, 0)
    STEP(1, 3, fbA0, fbA1, false, fbB0, fbB1, 0)

#undef STEP
#undef GENQ
#undef LOADB_INTO

    // ---- per-wave epilogue: lane holds n = n0+nt*16+ll, d = (2w+dtl)*16+lq*4+reg
    const float di0 = dinv[b * NN + n0 + ll];
    const float di1 = dinv[b * NN + n0 + 16 + ll];
    #pragma unroll
    for (int dtl = 0; dtl < 2; ++dtl) {
        const int d0 = (2 * w + dtl) * 16 + lq * 4;
        float4 bg4 = *(const float4*)&bg_l[d0];
        float sres[4] = {1.f, 1.f, 1.f, 1.f}, cres[4] = {0.f, 0.f, 0.f, 0.f};
        if (HP) {
            float4 ps4 = *(const float4*)&psumP[b * DD + d0];
            float4 pq4 = *(const float4*)&psqP[b * DD + d0];
            float4 ga4 = *(const float4*)&ga[d0];
            float4 gw4 = *(const float4*)&gw[d0];
            float4 gb4 = *(const float4*)&gb[d0];
            stats_sc(ps4.x, pq4.x, ga4.x, gw4.x, gb4.x, sres[0], cres[0]);
            stats_sc(ps4.y, pq4.y, ga4.y, gw4.y, gb4.y, sres[1], cres[1]);
            stats_sc(ps4.z, pq4.z, ga4.z, gw4.z, gb4.z, sres[2], cres[2]);
            stats_sc(ps4.w, pq4.w, ga4.w, gw4.w, gb4.w, sres[3], cres[3]);
        }
        float hs[4] = {0.f, 0.f, 0.f, 0.f}, hq[4] = {0.f, 0.f, 0.f, 0.f};
        #pragma unroll
        for (int nt = 0; nt < 2; ++nt) {
            const int n = n0 + nt * 16 + ll;
            const float di = nt ? di1 : di0;
            size_t idx = ((size_t)b * NN + n) * DD + d0;
            float4 hv = *(const float4*)&h[idx];
            float outv[4];
            #pragma unroll
            for (int r = 0; r < 4; ++r) {
                float pre = di * acc[nt][dtl][r] + (&bg4.x)[r];
                outv[r] = fast_tanh(pre) + fmaf(sres[r], (&hv.x)[r], cres[r]);
                hs[r] += outv[r];
                hq[r] += outv[r] * outv[r];
            }
            float4 ov = { outv[0], outv[1], outv[2], outv[3] };
            *(float4*)&h[idx] = ov;
        }

        // stats: reduce over the 16 ll lanes (32 n's already folded across nt)
        #pragma unroll
        for (int off = 1; off < 16; off <<= 1) {
            #pragma unroll
            for (int r = 0; r < 4; ++r) {
                hs[r] += __shfl_xor(hs[r], off);
                hq[r] += __shfl_xor(hq[r], off);
            }
        }
        if (ll == 0) {
            #pragma unroll
            for (int r = 0; r < 4; ++r) {
                atomicAdd(&psum[b * DD + d0 + r], hs[r]);
                atomicAdd(&psq[b * DD + d0 + r], hq[r]);
            }
        }
    }
}

// ---------------------------------------------------------------------------
// K5: final apply with in-thread stats from layer-2 buffers
// ---------------------------------------------------------------------------
__global__ __launch_bounds__(256)
void apply_kernel(const float* __restrict__ h,
                  const float* __restrict__ psum2, const float* __restrict__ psq2,
                  const float* __restrict__ ga, const float* __restrict__ gw,
                  const float* __restrict__ gb, float* __restrict__ dst)
{
    const int i4 = blockIdx.x * 256 + threadIdx.x;    // < B*N*D/4
    const int dg = (i4 & 31) * 4;
    const int b  = i4 >> 16;                          // N*D/4 = 65536
    float4 hv = ((const float4*)h)[i4];
    float o[4];
    #pragma unroll
    for (int j = 0; j < 4; ++j) {
        const int d = dg + j;
        float s, c;
        stats_sc(psum2[b * DD + d], psq2[b * DD + d], ga[d], gw[d], gb[d], s, c);
        o[j] = fmaf(s, (&hv.x)[j], c);
    }
    float4 ov = { o[0], o[1], o[2], o[3] };
    ((float4*)dst)[i4] = ov;
}

// ---------------------------------------------------------------------------
extern "C" void kernel_launch(void* const* d_in, const int* in_sizes, int n_in,
                              void* d_out, int out_size, void* d_ws, size_t ws_size,
                              hipStream_t stream)
{
    const float* inst = (const float*)d_in[0];
    const float* Wn   = (const float*)d_in[1];
    const float* bn   = (const float*)d_in[2];
    const float* Wg   = (const float*)d_in[3];
    const float* bg   = (const float*)d_in[4];
    const float* gw   = (const float*)d_in[5];
    const float* gb   = (const float*)d_in[6];
    const float* ga   = (const float*)d_in[7];
    float* out = (float*)d_out;

    float* ws   = (float*)d_ws;
    float* dinv = ws;                                   // B*N
    float* h    = dinv + BB * NN;                       // B*N*D
    float* psum = h + (size_t)BB * NN * DD;             // LL*B*D
    float* psq  = psum + LL * BB * DD;                  // LL*B*D
    float* weff = psq + LL * BB * DD;                   // 256 (Wg0·Wn fold)
    float* beff = weff + 2 * DD;                        // 128
    unsigned short* wgf = (unsigned short*)(beff + DD); // LL*D*D bf16
    unsigned short* tp  = wgf + LL * DD * DD;           // B*D*N bf16 (4MB)

    prep_wg<<<(LL * DD * DD) / 256, 256, 0, stream>>>(Wg, Wn, bn, wgf, weff, beff);
    gen_pack<<<1024, 256, 0, stream>>>(inst, Wn, bn, weff, beff, dinv, h, tp, psum, psq);

    // layer 0: tp0 already produced by gen_pack (lin0 folded)
    agg_mfma<false><<<512, 256, 0, stream>>>(
        inst, tp, dinv, bg + 0 * DD, nullptr, nullptr, ga, gw, gb, h, psum, psq);

    for (int l = 1; l < LL; ++l) {
        const unsigned short* wgl = wgf + (size_t)l * DD * DD;
        const float* psP = psum + (size_t)(l - 1) * BB * DD;
        const float* pqP = psq  + (size_t)(l - 1) * BB * DD;
        float* psL = psum + (size_t)l * BB * DD;
        float* pqL = psq  + (size_t)l * BB * DD;
        lin_mfma<true><<<(BB * NN) / 32, 256, 0, stream>>>(
            h, wgl, dinv, psP, pqP, ga, gw, gb, tp);
        agg_mfma<true><<<512, 256, 0, stream>>>(
            inst, tp, dinv, bg + l * DD, psP, pqP, ga, gw, gb, h, psL, pqL);
    }
    apply_kernel<<<(BB * NN * DD / 4) / 256, 256, 0, stream>>>(
        h, psum + 2 * BB * DD, psq + 2 * BB * DD, ga, gw, gb, out);
}

// Round 9
// 173.648 us; speedup vs baseline: 1.0275x; 1.0275x over previous
//
#include <hip/hip_runtime.h>
#include <hip/hip_bf16.h>
#include <math.h>

#define BB 8
#define NN 2048
#define DD 128
#define LL 3
#define GN_EPS 1e-5f

typedef __attribute__((ext_vector_type(8))) short bf16x8;
typedef __attribute__((ext_vector_type(4))) float f32x4;
typedef __attribute__((ext_vector_type(8))) unsigned short u16x8;

// raw v_sqrt_f32 (1 inst)
#define FSQRT(x) __builtin_amdgcn_sqrtf(x)

// round-half-up f32 -> bf16 bits
__device__ __forceinline__ unsigned short f2bf(float f) {
    union { float f; unsigned u; } v; v.f = f;
    return (unsigned short)((v.u + 0x8000u) >> 16);
}

__device__ __forceinline__ float fast_tanh(float x) {
    float e = __expf(-2.0f * fabsf(x));
    float t = (1.0f - e) * __builtin_amdgcn_rcpf(1.0f + e);
    return copysignf(t, x);
}

// GraphNorm affine fold: h_norm = s*h + c
__device__ __forceinline__ void stats_sc(float ps, float pq, float a, float w_,
                                         float b_, float& s, float& c) {
    const float inv_n = 1.0f / (float)NN;
    float mean = ps * inv_n;
    float msq  = pq * inv_n;
    float var  = msq - mean * mean * a * (2.0f - a);
    float rstd = rsqrtf(var + GN_EPS);
    s = w_ * rstd;
    c = b_ - s * (a * mean);
}

// Packed layout (16B granule = one lane's bf16x8 frag slice):
//  tp[b][kcg(64)][dt(8)][lane(64)]  value[j] = dinv*lin(h)[d=dt*16+ll][m=kcg*32+lq*8+j]
// A is never materialized in HBM: agg regenerates dist frags from coords in LDS.

// ---------------------------------------------------------------------------
// K0: prep_wg — pack Wg (3x128x128 f32) into bf16 MFMA frag order.
// Block 0 additionally folds layer-0 lin: Weff = Wg0·Wn (128x2, f32),
// beff = Wg0·bn — lets gen_pack emit tp0 directly (lin0 kernel removed).
// ---------------------------------------------------------------------------
__global__ __launch_bounds__(256)
void prep_wg(const float* __restrict__ Wg, const float* __restrict__ Wn,
             const float* __restrict__ bn, unsigned short* __restrict__ wgf,
             float* __restrict__ weff, float* __restrict__ beff)
{
    const int f = blockIdx.x * 256 + threadIdx.x;    // < 3*128*128
    const int l  = f >> 14;
    const int r  = f & 16383;
    const int dp = r >> 7;
    const int e  = r & 127;
    const int dpt = dp >> 4, ll = dp & 15;
    const int kc  = e >> 5,  eo = e & 31;
    wgf[((((l * 8 + dpt) * 4 + kc) * 16 + ll) << 5) + eo] = f2bf(Wg[f]);

    if (blockIdx.x == 0 && threadIdx.x < 128) {
        const int ee = threadIdx.x;
        float a0 = 0.f, a1 = 0.f, cc = 0.f;
        for (int d = 0; d < 128; ++d) {
            const float wv = Wg[ee * 128 + d];       // layer 0 slice
            a0 = fmaf(wv, Wn[d * 2 + 0], a0);
            a1 = fmaf(wv, Wn[d * 2 + 1], a1);
            cc = fmaf(wv, bn[d], cc);
        }
        weff[ee * 2 + 0] = a0;
        weff[ee * 2 + 1] = a1;
        beff[ee] = cc;
    }
}

// ---------------------------------------------------------------------------
// K1: gen_pack — deg/dinv (full dist row-sums, f32), proj_node h-init, and
// tp0 (layer-0 lin folded via Weff/beff).  NO Ap store — agg regenerates A.
// grid 1024 = [ntile(7b)<<3 | b(3b)].
// ---------------------------------------------------------------------------
__global__ __launch_bounds__(256)
void gen_pack(const float* __restrict__ inst, const float* __restrict__ Wn,
              const float* __restrict__ bn, const float* __restrict__ weff,
              const float* __restrict__ beff,
              float* __restrict__ dinv, float* __restrict__ h,
              unsigned short* __restrict__ tp,
              float* __restrict__ psum, float* __restrict__ psq)
{
    __shared__ float cs[NN * 2];          // 16 KB coords
    __shared__ float part[4][16];
    const int b     = blockIdx.x & 7;
    const int ntile = blockIdx.x >> 3;    // 0..127
    const int n0    = ntile * 16;
    const int tid   = threadIdx.x;
    const int w     = tid >> 6;
    const int lane  = tid & 63;
    const int lq    = lane >> 4;
    const int ll    = lane & 15;

    const float* instb = inst + b * NN * 2;
    for (int i = tid; i < (NN * 2) / 4; i += 256)
        ((float4*)cs)[i] = ((const float4*)instb)[i];
    __syncthreads();

    const int n = n0 + ll;
    const float nx = cs[n * 2 + 0];
    const float ny = cs[n * 2 + 1];

    const int diagkcg = ntile >> 1;       // kcg whose m-range contains n0..n0+15
    float rs = 0.f;
    for (int kc = 0; kc < 16; ++kc) {
        const int kcg = w * 16 + kc;
        const int mb  = kcg * 32 + lq * 8;
        const float* cp = &cs[mb * 2];
        float4 c01 = *(const float4*)(cp + 0);
        float4 c23 = *(const float4*)(cp + 4);
        float4 c45 = *(const float4*)(cp + 8);
        float4 c67 = *(const float4*)(cp + 12);
        float mxx[8] = { c01.x, c01.z, c23.x, c23.z, c45.x, c45.z, c67.x, c67.z };
        float myy[8] = { c01.y, c01.w, c23.y, c23.w, c45.y, c45.w, c67.y, c67.w };
        float dist[8];
        #pragma unroll
        for (int j = 0; j < 8; ++j) {
            float dx = nx - mxx[j];
            float dy = ny - myy[j];
            dist[j] = FSQRT(dx * dx + dy * dy);
        }
        if (kcg == diagkcg) {
            #pragma unroll
            for (int j = 0; j < 8; ++j)
                if (mb + j == n) dist[j] = 1.0f;       // self-loop
        }
        #pragma unroll
        for (int j = 0; j < 8; ++j) rs += dist[j];
    }

    rs += __shfl_xor(rs, 16);
    rs += __shfl_xor(rs, 32);
    if (lq == 0) part[w][ll] = rs;
    __syncthreads();
    if (tid < 16)
        dinv[b * NN + n0 + tid] = rsqrtf(part[0][tid] + part[1][tid] +
                                         part[2][tid] + part[3][tid]);

    // fused proj h-init + tp0 (layer-0 lin folded, dinv from part[])
    {
        const int d  = tid & 127;
        const int r0 = tid >> 7;          // 0/1
        const float w0 = Wn[d * 2 + 0];
        const float w1 = Wn[d * 2 + 1];
        const float bv = bn[d];
        const float we0 = weff[d * 2 + 0];
        const float we1 = weff[d * 2 + 1];
        const float be  = beff[d];
        const int kcg   = ntile >> 1;
        const int mbase = (ntile & 1) * 16;
        const int dt    = d >> 4;
        const int lld   = d & 15;
        unsigned short* tpd =
            tp + (((size_t)(b * 64 + kcg) * 8 + dt) * 64 + lld) * 8;
        #pragma unroll
        for (int r = r0; r < 16; r += 2) {
            const float x0 = cs[(n0 + r) * 2 + 0];
            const float x1 = cs[(n0 + r) * 2 + 1];
            h[((size_t)b * NN + n0 + r) * DD + d] = fmaf(x0, w0, fmaf(x1, w1, bv));
            const float dv = rsqrtf(part[0][r] + part[1][r] + part[2][r] + part[3][r]);
            const int mloc = mbase + r;
            const int lqa  = mloc >> 3;
            const int j    = mloc & 7;
            tpd[(size_t)lqa * 128 + j] = f2bf(dv * fmaf(x0, we0, fmaf(x1, we1, be)));
        }
    }
    if (blockIdx.x == 0) {
        for (int i = tid; i < LL * BB * DD; i += 256) { psum[i] = 0.f; psq[i] = 0.f; }
    }
}

// ---------------------------------------------------------------------------
// K3: lin (MFMA).  Writes tp in agg's packed frag order.  (layers 1,2 only)
// blockIdx = [tile(6b)<<3 | b(3b)] (batch -> XCD, same as agg).
// ---------------------------------------------------------------------------
template <bool HP>
__global__ __launch_bounds__(256)
void lin_mfma(const float* __restrict__ h, const unsigned short* __restrict__ wgf_l,
              const float* __restrict__ dinv,
              const float* __restrict__ psumP, const float* __restrict__ psqP,
              const float* __restrict__ ga, const float* __restrict__ gw,
              const float* __restrict__ gb, unsigned short* __restrict__ tp)
{
    __shared__ float sL[DD], cL[DD];
    const int tid  = threadIdx.x;
    const int b    = blockIdx.x & 7;
    const int tile = blockIdx.x >> 3;
    const int row0 = b * NN + tile * 32;
    const int w    = tid >> 6;
    const int lane = tid & 63;
    const int lq   = lane >> 4;
    const int ll   = lane & 15;

    if (tid < DD) {
        float s = 1.0f, c = 0.0f;
        if (HP)
            stats_sc(psumP[b * DD + tid], psqP[b * DD + tid],
                     ga[tid], gw[tid], gb[tid], s, c);
        sL[tid] = s; cL[tid] = c;
    }
    __syncthreads();

    bf16x8 aw[2][4];
    #pragma unroll
    for (int mt = 0; mt < 2; ++mt) {
        const int dpt = 2 * w + mt;
        #pragma unroll
        for (int kc = 0; kc < 4; ++kc)
            aw[mt][kc] = *(const bf16x8*)&wgf_l[(((dpt * 4 + kc) * 16 + ll) << 5) + lq * 8];
    }

    bf16x8 bh[2][4];
    #pragma unroll
    for (int nt = 0; nt < 2; ++nt) {
        const float* hrow = h + (size_t)(row0 + nt * 16 + ll) * DD;
        #pragma unroll
        for (int kc = 0; kc < 4; ++kc) {
            float4 h0 = *(const float4*)&hrow[kc * 32 + lq * 8];
            float4 h1 = *(const float4*)&hrow[kc * 32 + lq * 8 + 4];
            const int e0 = kc * 32 + lq * 8;
            bf16x8 p;
            p[0] = (short)f2bf(fmaf(sL[e0 + 0], h0.x, cL[e0 + 0]));
            p[1] = (short)f2bf(fmaf(sL[e0 + 1], h0.y, cL[e0 + 1]));
            p[2] = (short)f2bf(fmaf(sL[e0 + 2], h0.z, cL[e0 + 2]));
            p[3] = (short)f2bf(fmaf(sL[e0 + 3], h0.w, cL[e0 + 3]));
            p[4] = (short)f2bf(fmaf(sL[e0 + 4], h1.x, cL[e0 + 4]));
            p[5] = (short)f2bf(fmaf(sL[e0 + 5], h1.y, cL[e0 + 5]));
            p[6] = (short)f2bf(fmaf(sL[e0 + 6], h1.z, cL[e0 + 6]));
            p[7] = (short)f2bf(fmaf(sL[e0 + 7], h1.w, cL[e0 + 7]));
            bh[nt][kc] = p;
        }
    }

    f32x4 acc[2][2];   // [nt][mt]
    #pragma unroll
    for (int i = 0; i < 2; ++i)
        #pragma unroll
        for (int j = 0; j < 2; ++j) acc[i][j] = (f32x4)0.0f;

    #pragma unroll
    for (int kc = 0; kc < 4; ++kc)
        #pragma unroll
        for (int nt = 0; nt < 2; ++nt)
            #pragma unroll
            for (int mt = 0; mt < 2; ++mt)
                acc[nt][mt] = __builtin_amdgcn_mfma_f32_16x16x32_bf16(
                    bh[nt][kc], aw[mt][kc], acc[nt][mt], 0, 0, 0);

    // packed store: value (dp=(2w+mt)*16+ll, m = tile*32+nt*16+lq*4+reg)
    #pragma unroll
    for (int nt = 0; nt < 2; ++nt) {
        const int mloc0 = nt * 16 + lq * 4;            // m within the kcg=tile chunk
        const int lq_a  = mloc0 >> 3;
        const int j0    = mloc0 & 7;
        float4 di4 = *(const float4*)&dinv[row0 + mloc0];
        #pragma unroll
        for (int mt = 0; mt < 2; ++mt) {
            const int dt = 2 * w + mt;
            ushort4 pk;
            pk.x = f2bf(acc[nt][mt][0] * di4.x);
            pk.y = f2bf(acc[nt][mt][1] * di4.y);
            pk.z = f2bf(acc[nt][mt][2] * di4.z);
            pk.w = f2bf(acc[nt][mt][3] * di4.w);
            *(ushort4*)&tp[((size_t)((b * 64 + tile) * 8 + dt) * 64 + lq_a * 16 + ll) * 8 + j0] = pk;
        }
    }
}

// ---------------------------------------------------------------------------
// K4: agg — 32n x 128d tile, grid 512 (2 blocks/CU), 256 thr.
// K-SPLIT ACROSS WAVES (barrier-free K-loop): wave w owns kcg w*16..w*16+15,
// computes its dist frags IN REGISTERS (identical per-lane values to the old
// LDS-plane path — the plane round-trip was a same-lane identity, needed only
// because the old d-split made every wave consume every kcg).  Each wave
// accumulates a partial acc[nt=2][dt=8] over its K-quarter with zero
// syncthreads and no A-frag LDS traffic, then ONE LDS reduction (64 KB,
// write + barrier + read-sum) and the unchanged per-wave epilogue on its
// d-slice.  f32 reassociation only (4x16-kcg partials) — ~1e-6 relative.
// LDS 80 KB = 16 coords + 64 reduce; 2 blocks/CU; B double-buffered in regs.
// ---------------------------------------------------------------------------
template <bool HP>
__global__ __launch_bounds__(256, 2)
void agg_mfma(const float* __restrict__ inst, const unsigned short* __restrict__ tp,
              const float* __restrict__ dinv, const float* __restrict__ bg_l,
              const float* __restrict__ psumP, const float* __restrict__ psqP,
              const float* __restrict__ ga, const float* __restrict__ gw,
              const float* __restrict__ gb,
              float* __restrict__ h, float* __restrict__ psum, float* __restrict__ psq)
{
    __shared__ float cs[NN * 2];                    // 16 KB coords
    __shared__ __align__(16) char red[65536];       // 64 KB partial-acc reduce
    const int b    = blockIdx.x & 7;
    const int t2   = blockIdx.x >> 3;     // 0..63 (32-row tile)
    const int n0   = t2 * 32;
    const int tid  = threadIdx.x;
    const int w    = tid >> 6;
    const int lane = tid & 63;
    const int lq   = lane >> 4;
    const int ll   = lane & 15;

    // stage coords
    const float* instb = inst + b * NN * 2;
    for (int i = tid; i < (NN * 2) / 4; i += 256)
        ((float4*)cs)[i] = ((const float4*)instb)[i];

    const unsigned short* tpb = tp + ((size_t)b * 64 * 8) * 512 + lane * 8;

    f32x4 acc[2][8];   // [nt][dt] — partial over this wave's kcg quarter
    #pragma unroll
    for (int nt = 0; nt < 2; ++nt)
        #pragma unroll
        for (int dt = 0; dt < 8; ++dt) acc[nt][dt] = (f32x4)0.0f;

    bf16x8 fbE[8], fbO[8];   // B double buffer (8 dt frags each)

    __syncthreads();      // coords visible

    // this lane's two output rows (nt=0/1) — diag lives at kcg == t2
    const int   nr0 = n0 + ll;
    const int   nr1 = n0 + 16 + ll;
    const float nx0 = cs[nr0 * 2 + 0], ny0 = cs[nr0 * 2 + 1];
    const float nx1 = cs[nr1 * 2 + 0], ny1 = cs[nr1 * 2 + 1];

    const int kcg0 = w * 16;   // this wave's K-quarter

#define LOADB(DST, KCG) { \
        _Pragma("unroll") \
        for (int dt_ = 0; dt_ < 8; ++dt_) \
            DST[dt_] = *(const bf16x8*)(tpb + (size_t)((KCG) * 8 + dt_) * 512); \
    }

    // One K-step: GEN af (registers), prefetch next B, 16 MFMA.
#define STEPK(KC, CUR, NXT, DOLOAD) { \
        const int kcg_ = kcg0 + (KC); \
        const int mb_  = kcg_ * 32 + lq * 8; \
        const float* cp_ = &cs[mb_ * 2]; \
        float4 c01 = *(const float4*)(cp_ + 0); \
        float4 c23 = *(const float4*)(cp_ + 4); \
        float4 c45 = *(const float4*)(cp_ + 8); \
        float4 c67 = *(const float4*)(cp_ + 12); \
        float mxx[8] = { c01.x, c01.z, c23.x, c23.z, c45.x, c45.z, c67.x, c67.z }; \
        float myy[8] = { c01.y, c01.w, c23.y, c23.w, c45.y, c45.w, c67.y, c67.w }; \
        float dv0[8], dv1[8]; \
        _Pragma("unroll") \
        for (int j = 0; j < 8; ++j) { \
            float dx0 = nx0 - mxx[j], dy0 = ny0 - myy[j]; \
            dv0[j] = FSQRT(dx0 * dx0 + dy0 * dy0); \
            float dx1 = nx1 - mxx[j], dy1 = ny1 - myy[j]; \
            dv1[j] = FSQRT(dx1 * dx1 + dy1 * dy1); \
        } \
        if (kcg_ == t2) {   /* wave-uniform diag fixup */ \
            _Pragma("unroll") \
            for (int j = 0; j < 8; ++j) { \
                if (mb_ + j == nr0) dv0[j] = 1.0f; \
                if (mb_ + j == nr1) dv1[j] = 1.0f; \
            } \
        } \
        bf16x8 af0, af1; \
        _Pragma("unroll") \
        for (int j = 0; j < 8; ++j) { \
            af0[j] = (short)f2bf(dv0[j]); \
            af1[j] = (short)f2bf(dv1[j]); \
        } \
        if (DOLOAD) LOADB(NXT, kcg_ + 1) \
        _Pragma("unroll") \
        for (int dt_ = 0; dt_ < 8; ++dt_) { \
            acc[0][dt_] = __builtin_amdgcn_mfma_f32_16x16x32_bf16(CUR[dt_], af0, acc[0][dt_], 0, 0, 0); \
            acc[1][dt_] = __builtin_amdgcn_mfma_f32_16x16x32_bf16(CUR[dt_], af1, acc[1][dt_], 0, 0, 0); \
        } \
    }

    LOADB(fbE, kcg0)
    STEPK(0,  fbE, fbO, true)
    STEPK(1,  fbO, fbE, true)
    STEPK(2,  fbE, fbO, true)
    STEPK(3,  fbO, fbE, true)
    STEPK(4,  fbE, fbO, true)
    STEPK(5,  fbO, fbE, true)
    STEPK(6,  fbE, fbO, true)
    STEPK(7,  fbO, fbE, true)
    STEPK(8,  fbE, fbO, true)
    STEPK(9,  fbO, fbE, true)
    STEPK(10, fbE, fbO, true)
    STEPK(11, fbO, fbE, true)
    STEPK(12, fbE, fbO, true)
    STEPK(13, fbO, fbE, true)
    STEPK(14, fbE, fbO, true)
    STEPK(15, fbO, fbE, false)
#undef STEPK
#undef LOADB

    // ---- cross-wave K-reduction: red slot (dt*2+nt)*4 + w, 1 KB each
    #pragma unroll
    for (int nt = 0; nt < 2; ++nt)
        #pragma unroll
        for (int dt = 0; dt < 8; ++dt)
            *(f32x4*)(red + (((dt * 2 + nt) * 4 + w) * 1024) + lane * 16) = acc[nt][dt];
    __syncthreads();

    f32x4 accs[2][2];   // [nt][dtl] — summed over the 4 K-quarters
    #pragma unroll
    for (int dtl = 0; dtl < 2; ++dtl) {
        const int dt = 2 * w + dtl;
        #pragma unroll
        for (int nt = 0; nt < 2; ++nt) {
            f32x4 r0 = *(const f32x4*)(red + (((dt * 2 + nt) * 4 + 0) * 1024) + lane * 16);
            f32x4 r1 = *(const f32x4*)(red + (((dt * 2 + nt) * 4 + 1) * 1024) + lane * 16);
            f32x4 r2 = *(const f32x4*)(red + (((dt * 2 + nt) * 4 + 2) * 1024) + lane * 16);
            f32x4 r3 = *(const f32x4*)(red + (((dt * 2 + nt) * 4 + 3) * 1024) + lane * 16);
            accs[nt][dtl] = ((r0 + r1) + r2) + r3;
        }
    }

    // ---- per-wave epilogue: lane holds n = n0+nt*16+ll, d = (2w+dtl)*16+lq*4+reg
    const float di0 = dinv[b * NN + n0 + ll];
    const float di1 = dinv[b * NN + n0 + 16 + ll];
    #pragma unroll
    for (int dtl = 0; dtl < 2; ++dtl) {
        const int d0 = (2 * w + dtl) * 16 + lq * 4;
        float4 bg4 = *(const float4*)&bg_l[d0];
        float sres[4] = {1.f, 1.f, 1.f, 1.f}, cres[4] = {0.f, 0.f, 0.f, 0.f};
        if (HP) {
            float4 ps4 = *(const float4*)&psumP[b * DD + d0];
            float4 pq4 = *(const float4*)&psqP[b * DD + d0];
            float4 ga4 = *(const float4*)&ga[d0];
            float4 gw4 = *(const float4*)&gw[d0];
            float4 gb4 = *(const float4*)&gb[d0];
            stats_sc(ps4.x, pq4.x, ga4.x, gw4.x, gb4.x, sres[0], cres[0]);
            stats_sc(ps4.y, pq4.y, ga4.y, gw4.y, gb4.y, sres[1], cres[1]);
            stats_sc(ps4.z, pq4.z, ga4.z, gw4.z, gb4.z, sres[2], cres[2]);
            stats_sc(ps4.w, pq4.w, ga4.w, gw4.w, gb4.w, sres[3], cres[3]);
        }
        float hs[4] = {0.f, 0.f, 0.f, 0.f}, hq[4] = {0.f, 0.f, 0.f, 0.f};
        #pragma unroll
        for (int nt = 0; nt < 2; ++nt) {
            const int n = n0 + nt * 16 + ll;
            const float di = nt ? di1 : di0;
            size_t idx = ((size_t)b * NN + n) * DD + d0;
            float4 hv = *(const float4*)&h[idx];
            float outv[4];
            #pragma unroll
            for (int r = 0; r < 4; ++r) {
                float pre = di * accs[nt][dtl][r] + (&bg4.x)[r];
                outv[r] = fast_tanh(pre) + fmaf(sres[r], (&hv.x)[r], cres[r]);
                hs[r] += outv[r];
                hq[r] += outv[r] * outv[r];
            }
            float4 ov = { outv[0], outv[1], outv[2], outv[3] };
            *(float4*)&h[idx] = ov;
        }

        // stats: reduce over the 16 ll lanes (32 n's already folded across nt)
        #pragma unroll
        for (int off = 1; off < 16; off <<= 1) {
            #pragma unroll
            for (int r = 0; r < 4; ++r) {
                hs[r] += __shfl_xor(hs[r], off);
                hq[r] += __shfl_xor(hq[r], off);
            }
        }
        if (ll == 0) {
            #pragma unroll
            for (int r = 0; r < 4; ++r) {
                atomicAdd(&psum[b * DD + d0 + r], hs[r]);
                atomicAdd(&psq[b * DD + d0 + r], hq[r]);
            }
        }
    }
}

// ---------------------------------------------------------------------------
// K5: final apply with in-thread stats from layer-2 buffers
// ---------------------------------------------------------------------------
__global__ __launch_bounds__(256)
void apply_kernel(const float* __restrict__ h,
                  const float* __restrict__ psum2, const float* __restrict__ psq2,
                  const float* __restrict__ ga, const float* __restrict__ gw,
                  const float* __restrict__ gb, float* __restrict__ dst)
{
    const int i4 = blockIdx.x * 256 + threadIdx.x;    // < B*N*D/4
    const int dg = (i4 & 31) * 4;
    const int b  = i4 >> 16;                          // N*D/4 = 65536
    float4 hv = ((const float4*)h)[i4];
    float o[4];
    #pragma unroll
    for (int j = 0; j < 4; ++j) {
        const int d = dg + j;
        float s, c;
        stats_sc(psum2[b * DD + d], psq2[b * DD + d], ga[d], gw[d], gb[d], s, c);
        o[j] = fmaf(s, (&hv.x)[j], c);
    }
    float4 ov = { o[0], o[1], o[2], o[3] };
    ((float4*)dst)[i4] = ov;
}

// ---------------------------------------------------------------------------
extern "C" void kernel_launch(void* const* d_in, const int* in_sizes, int n_in,
                              void* d_out, int out_size, void* d_ws, size_t ws_size,
                              hipStream_t stream)
{
    const float* inst = (const float*)d_in[0];
    const float* Wn   = (const float*)d_in[1];
    const float* bn   = (const float*)d_in[2];
    const float* Wg   = (const float*)d_in[3];
    const float* bg   = (const float*)d_in[4];
    const float* gw   = (const float*)d_in[5];
    const float* gb   = (const float*)d_in[6];
    const float* ga   = (const float*)d_in[7];
    float* out = (float*)d_out;

    float* ws   = (float*)d_ws;
    float* dinv = ws;                                   // B*N
    float* h    = dinv + BB * NN;                       // B*N*D
    float* psum = h + (size_t)BB * NN * DD;             // LL*B*D
    float* psq  = psum + LL * BB * DD;                  // LL*B*D
    float* weff = psq + LL * BB * DD;                   // 256 (Wg0·Wn fold)
    float* beff = weff + 2 * DD;                        // 128
    unsigned short* wgf = (unsigned short*)(beff + DD); // LL*D*D bf16
    unsigned short* tp  = wgf + LL * DD * DD;           // B*D*N bf16 (4MB)

    prep_wg<<<(LL * DD * DD) / 256, 256, 0, stream>>>(Wg, Wn, bn, wgf, weff, beff);
    gen_pack<<<1024, 256, 0, stream>>>(inst, Wn, bn, weff, beff, dinv, h, tp, psum, psq);

    // layer 0: tp0 already produced by gen_pack (lin0 folded)
    agg_mfma<false><<<512, 256, 0, stream>>>(
        inst, tp, dinv, bg + 0 * DD, nullptr, nullptr, ga, gw, gb, h, psum, psq);

    for (int l = 1; l < LL; ++l) {
        const unsigned short* wgl = wgf + (size_t)l * DD * DD;
        const float* psP = psum + (size_t)(l - 1) * BB * DD;
        const float* pqP = psq  + (size_t)(l - 1) * BB * DD;
        float* psL = psum + (size_t)l * BB * DD;
        float* pqL = psq  + (size_t)l * BB * DD;
        lin_mfma<true><<<(BB * NN) / 32, 256, 0, stream>>>(
            h, wgl, dinv, psP, pqP, ga, gw, gb, tp);
        agg_mfma<true><<<512, 256, 0, stream>>>(
            inst, tp, dinv, bg + l * DD, psP, pqP, ga, gw, gb, h, psL, pqL);
    }
    apply_kernel<<<(BB * NN * DD / 4) / 256, 256, 0, stream>>>(
        h, psum + 2 * BB * DD, psq + 2 * BB * DD, ga, gw, gb, out);
}